// Round 8
// baseline (285.884 us; speedup 1.0000x reference)
//
#include <hip/hip_runtime.h>
#include <stdint.h>

typedef unsigned short u16;
typedef unsigned int   u32;
typedef _Float16       f16;

typedef __attribute__((ext_vector_type(2))) _Float16 half2v;
typedef __attribute__((ext_vector_type(4))) _Float16 half4v;
typedef __attribute__((ext_vector_type(8))) _Float16 half8v;
typedef __attribute__((ext_vector_type(4))) float    floatx4;

#define NXS    512
#define NYS    512
#define NHEAD  8
#define DHEAD  10
#define DMODEL 80
#define DXK    768
#define DYK    283
#define DYKP   288   // padded

__device__ inline half2v pk2(float x, float y) {
  return __builtin_bit_cast(half2v, __builtin_amdgcn_cvt_pkrtz(x, y));
}
__device__ inline half4v cvt4(float4 v) {
  return __builtin_shufflevector(pk2(v.x, v.y), pk2(v.z, v.w), 0, 1, 2, 3);
}
__device__ inline half4v h4u32(u32 a, u32 b) {
  return __builtin_shufflevector(__builtin_bit_cast(half2v, a),
                                 __builtin_bit_cast(half2v, b), 0, 1, 2, 3);
}

// =====================================================================
// w_prep: transpose + fp32->f16 weights. Tq[c][k] (80x768),
// Tk/Tv[c][k] (80x288, zero-padded past k=283).
// =====================================================================
__global__ __launch_bounds__(256) void w_prep(const float* __restrict__ Wq,
                                              const float* __restrict__ Wk,
                                              const float* __restrict__ Wv,
                                              f16* __restrict__ Tq,
                                              f16* __restrict__ Tk,
                                              f16* __restrict__ Tv) {
  const int idx = blockIdx.x * 256 + threadIdx.x;
  if (idx < 80 * 768) {
    const int c = idx / 768, k = idx - c * 768;
    Tq[idx] = (f16)Wq[k * 80 + c];
  }
  if (idx < 80 * 288) {
    const int c = idx / 288, k = idx - c * 288;
    float a = 0.f, b = 0.f;
    if (k < DYK) { a = Wk[k * 80 + c]; b = Wv[k * 80 + c]; }
    Tk[idx] = (f16)a;
    Tv[idx] = (f16)b;
  }
}

// =====================================================================
// proj (merged): LDS-staged with DEEP register prefetch (3-deep on Q
// path, 2-deep on KV) so the vmcnt wait before ds_write lands on loads
// issued >=2 iterations earlier. Single union'd LDS block (17920 B =
// max of branches, not sum). All outputs f16 in [row][80] layout
// (coalesced 32B runs). blocks 0..511 = Q, 512..1023 = KV.
// =====================================================================
__global__ __launch_bounds__(256) void proj(const float* __restrict__ X,
                                            const float* __restrict__ Y,
                                            const f16* __restrict__ Wtq,
                                            const f16* __restrict__ Wtk,
                                            const f16* __restrict__ Wtv,
                                            f16* __restrict__ Qw,
                                            f16* __restrict__ Kw,
                                            f16* __restrict__ Vw) {
  __shared__ __align__(16) char smem[17920];
  const int t = threadIdx.x;
  const int wv = t >> 6, lane = t & 63, m16 = lane & 15, quad = lane >> 4;
  const int blk = blockIdx.x;

  if (blk < 512) {
    // ---------------- Q path ----------------
    f16* Xs = (f16*)smem;            // 64*40
    f16* Ws = (f16*)(smem + 5120);   // 80*40
    const int row0 = blk * 64;
    const int xr_r = t >> 3, xr_k = (t & 7) << 2;
    const int wi0 = t, wi1 = t + 160;

    float4 xa[3], xb[3];
    uint4 wr0[3], wr1[3];
#pragma unroll
    for (int j = 0; j < 3; ++j) {
      const int k0 = j * 32;
      xa[j] = *(const float4*)&X[(size_t)(row0 + xr_r) * DXK + k0 + xr_k];
      xb[j] = *(const float4*)&X[(size_t)(row0 + xr_r + 32) * DXK + k0 + xr_k];
      if (t < 160) {
        wr0[j] = *(const uint4*)&Wtq[(wi0 >> 2) * DXK + k0 + (wi0 & 3) * 8];
        wr1[j] = *(const uint4*)&Wtq[(wi1 >> 2) * DXK + k0 + (wi1 & 3) * 8];
      }
    }

    floatx4 acc[5];
#pragma unroll
    for (int i = 0; i < 5; ++i) acc[i] = (floatx4){0.f, 0.f, 0.f, 0.f};

#pragma unroll 3
    for (int s = 0; s < 24; ++s) {
      const int j = s % 3;
      if (s) __syncthreads();
      *(half4v*)&Xs[xr_r * 40 + xr_k] = cvt4(xa[j]);
      *(half4v*)&Xs[(xr_r + 32) * 40 + xr_k] = cvt4(xb[j]);
      if (t < 160) {
        *(uint4*)&Ws[(wi0 >> 2) * 40 + (wi0 & 3) * 8] = wr0[j];
        *(uint4*)&Ws[(wi1 >> 2) * 40 + (wi1 & 3) * 8] = wr1[j];
      }
      __syncthreads();
      if (s + 3 < 24) {
        const int k0 = (s + 3) * 32;
        xa[j] = *(const float4*)&X[(size_t)(row0 + xr_r) * DXK + k0 + xr_k];
        xb[j] = *(const float4*)&X[(size_t)(row0 + xr_r + 32) * DXK + k0 + xr_k];
        if (t < 160) {
          wr0[j] = *(const uint4*)&Wtq[(wi0 >> 2) * DXK + k0 + (wi0 & 3) * 8];
          wr1[j] = *(const uint4*)&Wtq[(wi1 >> 2) * DXK + k0 + (wi1 & 3) * 8];
        }
      }
      const half8v a = *(const half8v*)&Xs[(wv * 16 + m16) * 40 + quad * 8];
#pragma unroll
      for (int nt = 0; nt < 5; ++nt) {
        const half8v b = *(const half8v*)&Ws[(nt * 16 + m16) * 40 + quad * 8];
        acc[nt] = __builtin_amdgcn_mfma_f32_16x16x32_f16(a, b, acc[nt], 0, 0, 0);
      }
    }
#pragma unroll
    for (int nt = 0; nt < 5; ++nt) {
      const int col = nt * 16 + m16;
#pragma unroll
      for (int p = 0; p < 4; ++p) {
        const int grow = row0 + wv * 16 + quad * 4 + p;
        Qw[(size_t)grow * DMODEL + col] = (f16)acc[nt][p];
      }
    }
  } else {
    // ---------------- KV path ----------------
    f16* Ys  = (f16*)smem;            // 64*40
    f16* Wks = (f16*)(smem + 5120);   // 80*40
    f16* Wvs = (f16*)(smem + 11520);  // 80*40
    const int row0 = (blk - 512) * 64;
    const int wi0 = t, wi1 = t + 160;

    float yr[2][8];
    uint4 wk0[2], wk1[2], wv0[2], wv1[2];
#pragma unroll
    for (int j = 0; j < 2; ++j) {
      const int k0 = j * 32;
#pragma unroll
      for (int i = 0; i < 8; ++i) {
        const int idx = t + 256 * i;
        const int r = idx >> 5, kk = idx & 31;
        yr[j][i] = Y[(size_t)(row0 + r) * DYK + k0 + kk];
      }
      if (t < 160) {
        wk0[j] = *(const uint4*)&Wtk[(wi0 >> 2) * DYKP + k0 + (wi0 & 3) * 8];
        wk1[j] = *(const uint4*)&Wtk[(wi1 >> 2) * DYKP + k0 + (wi1 & 3) * 8];
        wv0[j] = *(const uint4*)&Wtv[(wi0 >> 2) * DYKP + k0 + (wi0 & 3) * 8];
        wv1[j] = *(const uint4*)&Wtv[(wi1 >> 2) * DYKP + k0 + (wi1 & 3) * 8];
      }
    }

    floatx4 ak[5], av[5];
#pragma unroll
    for (int i = 0; i < 5; ++i) {
      ak[i] = (floatx4){0.f, 0.f, 0.f, 0.f};
      av[i] = (floatx4){0.f, 0.f, 0.f, 0.f};
    }

#pragma unroll 2
    for (int s = 0; s < 9; ++s) {
      const int j = s & 1;
      if (s) __syncthreads();
#pragma unroll
      for (int i = 0; i < 8; ++i) {
        const int idx = t + 256 * i;
        Ys[(idx >> 5) * 40 + (idx & 31)] = (f16)yr[j][i];
      }
      if (t < 160) {
        *(uint4*)&Wks[(wi0 >> 2) * 40 + (wi0 & 3) * 8] = wk0[j];
        *(uint4*)&Wks[(wi1 >> 2) * 40 + (wi1 & 3) * 8] = wk1[j];
        *(uint4*)&Wvs[(wi0 >> 2) * 40 + (wi0 & 3) * 8] = wv0[j];
        *(uint4*)&Wvs[(wi1 >> 2) * 40 + (wi1 & 3) * 8] = wv1[j];
      }
      __syncthreads();
      if (s + 2 < 9) {
        const int k0 = (s + 2) * 32;
        if (s + 2 < 8) {
#pragma unroll
          for (int i = 0; i < 8; ++i) {
            const int idx = t + 256 * i;
            yr[j][i] = Y[(size_t)(row0 + (idx >> 5)) * DYK + k0 + (idx & 31)];
          }
        } else {
#pragma unroll
          for (int i = 0; i < 8; ++i) {
            const int idx = t + 256 * i;
            const int k = k0 + (idx & 31);
            yr[j][i] = (k < DYK) ? Y[(size_t)(row0 + (idx >> 5)) * DYK + k] : 0.f;
          }
        }
        if (t < 160) {
          wk0[j] = *(const uint4*)&Wtk[(wi0 >> 2) * DYKP + k0 + (wi0 & 3) * 8];
          wk1[j] = *(const uint4*)&Wtk[(wi1 >> 2) * DYKP + k0 + (wi1 & 3) * 8];
          wv0[j] = *(const uint4*)&Wtv[(wi0 >> 2) * DYKP + k0 + (wi0 & 3) * 8];
          wv1[j] = *(const uint4*)&Wtv[(wi1 >> 2) * DYKP + k0 + (wi1 & 3) * 8];
        }
      }
      const half8v a = *(const half8v*)&Ys[(wv * 16 + m16) * 40 + quad * 8];
#pragma unroll
      for (int nt = 0; nt < 5; ++nt) {
        const half8v bk = *(const half8v*)&Wks[(nt * 16 + m16) * 40 + quad * 8];
        ak[nt] = __builtin_amdgcn_mfma_f32_16x16x32_f16(a, bk, ak[nt], 0, 0, 0);
        const half8v bv = *(const half8v*)&Wvs[(nt * 16 + m16) * 40 + quad * 8];
        av[nt] = __builtin_amdgcn_mfma_f32_16x16x32_f16(a, bv, av[nt], 0, 0, 0);
      }
    }
#pragma unroll
    for (int nt = 0; nt < 5; ++nt) {
      const int col = nt * 16 + m16;
#pragma unroll
      for (int p = 0; p < 4; ++p) {
        const int grow = row0 + wv * 16 + quad * 4 + p;
        Kw[(size_t)grow * DMODEL + col] = (f16)ak[nt][p];
        Vw[(size_t)grow * DMODEL + col] = (f16)av[nt][p];
      }
    }
  }
}

// =====================================================================
// attn: 2 blocks per (b,h) (grid 1024), 4 waves, 4 q-tiles/wave.
// K,V now in [row][80] layout (h*5 u32 offset per row, row stride 40 u32,
// L2-hot from proj). K,V^T staged in LDS (odd-dword strides 22 / 522);
// dual accumulators; no-max softmax with pre-scaled q.
// =====================================================================
__global__ __launch_bounds__(256) void attn(const f16* __restrict__ Q,
                                            const f16* __restrict__ K,
                                            const f16* __restrict__ V,
                                            float* __restrict__ O) {
  __shared__ f16 Ks[512 * 22];   // [key][d], d 10..15 zeroed
  __shared__ f16 Vt[16 * 522];   // [d][key], d rows 10..15 zeroed
  const int t = threadIdx.x;
  const int wv = t >> 6, lane = t & 63, m16 = lane & 15, quad = lane >> 4;
  const int bh = blockIdx.x >> 1, half = blockIdx.x & 1;
  const int b = bh >> 3, h = bh & 7;

  const u32* Kg = (const u32*)K + (size_t)b * NXS * 40 + h * 5;
  const u32* Vg = (const u32*)V + (size_t)b * NXS * 40 + h * 5;
  for (int idx = t; idx < 2560; idx += 256) {
    const u32 row = (u32)idx / 5u, c = (u32)idx - row * 5u;
    const half2v kv = __builtin_bit_cast(half2v, Kg[row * 40 + c]);
    Ks[row * 22 + 2 * c]     = kv[0];
    Ks[row * 22 + 2 * c + 1] = kv[1];
    const half2v vvv = __builtin_bit_cast(half2v, Vg[row * 40 + c]);
    Vt[(2 * c) * 522 + row]     = vvv[0];
    Vt[(2 * c + 1) * 522 + row] = vvv[1];
  }
  for (int idx = t; idx < 3072; idx += 256) {  // Ks d-pad 10..15
    const u32 row = (u32)idx / 6u, d = 10u + ((u32)idx - row * 6u);
    Ks[row * 22 + d] = (f16)0.f;
  }
  for (int idx = t; idx < 6 * 522; idx += 256)  // Vt rows 10..15
    Vt[10 * 522 + idx] = (f16)0.f;
  __syncthreads();

  const float scale = 0.31622776601683794f;  // 1/sqrt(10)
#pragma unroll 1
  for (int i = 0; i < 4; ++i) {
    const int qt = half * 16 + wv * 4 + i;
    const int qrow = qt * 16 + m16;
    const u32* Qg32 = (const u32*)(Q + ((size_t)b * NXS + qrow) * DMODEL + h * DHEAD);
    float s0 = 0.f, s1 = 0.f, s2 = 0.f, s3 = 0.f;
    if (quad < 2) {
      const u32 ua = Qg32[quad * 2], ub = Qg32[quad * 2 + 1];
      const half2v ha = __builtin_bit_cast(half2v, ua);
      const half2v hb = __builtin_bit_cast(half2v, ub);
      s0 = (float)ha[0]; s1 = (float)ha[1]; s2 = (float)hb[0]; s3 = (float)hb[1];
    } else if (quad == 2) {
      const u32 ua = Qg32[4];
      const half2v ha = __builtin_bit_cast(half2v, ua);
      s0 = (float)ha[0]; s1 = (float)ha[1];
    }
    const half4v qf = __builtin_shufflevector(pk2(s0 * scale, s1 * scale),
                                              pk2(s2 * scale, s3 * scale),
                                              0, 1, 2, 3);
    floatx4 o0 = (floatx4){0.f, 0.f, 0.f, 0.f};
    floatx4 o1 = (floatx4){0.f, 0.f, 0.f, 0.f};
    float l0 = 0.f, l1 = 0.f;
    for (int kt = 0; kt < 32; kt += 2) {
#pragma unroll
      for (int u = 0; u < 2; ++u) {
        const int ktu = kt + u;
        const int kb = (ktu * 16 + m16) * 22 + quad * 4;
        const half4v kf = h4u32(*(const u32*)&Ks[kb], *(const u32*)&Ks[kb + 2]);
        const floatx4 s = __builtin_amdgcn_mfma_f32_16x16x16f16(
            kf, qf, (floatx4){0.f, 0.f, 0.f, 0.f}, 0, 0, 0);
        const float p0 = __expf(s[0]);
        const float p1 = __expf(s[1]);
        const float p2 = __expf(s[2]);
        const float p3 = __expf(s[3]);
        const half4v pf = __builtin_shufflevector(pk2(p0, p1), pk2(p2, p3),
                                                  0, 1, 2, 3);
        const int vb = m16 * 522 + ktu * 16 + quad * 4;
        const half4v vf = h4u32(*(const u32*)&Vt[vb], *(const u32*)&Vt[vb + 2]);
        if (u == 0) {
          l0 += (p0 + p1) + (p2 + p3);
          o0 = __builtin_amdgcn_mfma_f32_16x16x16f16(pf, vf, o0, 0, 0, 0);
        } else {
          l1 += (p0 + p1) + (p2 + p3);
          o1 = __builtin_amdgcn_mfma_f32_16x16x16f16(pf, vf, o1, 0, 0, 0);
        }
      }
    }
    float lp = l0 + l1;
    lp += __shfl_xor(lp, 16);
    lp += __shfl_xor(lp, 32);
#pragma unroll
    for (int p = 0; p < 4; ++p) {
      const int rq = qt * 16 + quad * 4 + p;
      const float lr = __shfl(lp, quad * 4 + p);
      if (m16 < DHEAD) {
        const float qres = (float)Q[((size_t)b * NXS + rq) * DMODEL + h * DHEAD + m16];
        O[((size_t)b * NXS + rq) * DMODEL + h * DHEAD + m16] =
            qres + (o0[p] + o1[p]) / lr;
      }
    }
  }
}

extern "C" void kernel_launch(void* const* d_in, const int* in_sizes, int n_in,
                              void* d_out, int out_size, void* d_ws, size_t ws_size,
                              hipStream_t stream) {
  const float* x  = (const float*)d_in[0];
  const float* y  = (const float*)d_in[1];
  const float* Wq = (const float*)d_in[2];
  const float* Wk = (const float*)d_in[3];
  const float* Wv = (const float*)d_in[4];
  float* out = (float*)d_out;

  char* ws = (char*)d_ws;
  f16* Wtq = (f16*)(ws);                  // 80*768*2  = 122880 B
  f16* Wtk = (f16*)(ws + 122880);         // 80*288*2  =  46080 B
  f16* Wtv = (f16*)(ws + 168960);         // 46080 B
  f16* Qw  = (f16*)(ws + 262144);         // 5242880 B
  f16* Kw  = (f16*)(ws + 5505024);
  f16* Vw  = (f16*)(ws + 10747904);

  w_prep<<<240, 256, 0, stream>>>(Wq, Wk, Wv, Wtq, Wtk, Wtv);
  proj  <<<1024, 256, 0, stream>>>(x, y, Wtq, Wtk, Wtv, Qw, Kw, Vw);
  attn  <<<1024, 256, 0, stream>>>(Qw, Kw, Vw, out);
}